// Round 1
// baseline (742.177 us; speedup 1.0000x reference)
//
#include <hip/hip_runtime.h>

#define K 11
#define PAD 5          // K/2
#define TILE 16
#define REG (TILE + K - 1)   // 26

// SSIM fused kernel: clip -> 5 depthwise separable 11x11 convs -> ssim map -> sum
__global__ __launch_bounds__(256) void ssim_kernel(
    const float* __restrict__ img1, const float* __restrict__ img2,
    const float* __restrict__ window, float* __restrict__ acc,
    int H, int W, int C)
{
    __shared__ float2 tile[REG][REG];   // clipped (x1, x2), zero outside image
    __shared__ float gwin[K];           // 1-D gaussian (row sums of 2-D window)
    __shared__ float v1[TILE][REG], v2[TILE][REG];
    __shared__ float v11[TILE][REG], v22[TILE][REG], v12[TILE][REG];
    __shared__ float wsum[4];

    const int tx = threadIdx.x, ty = threadIdx.y;
    const int tid = ty * TILE + tx;
    const int bz = blockIdx.z;
    const int c = bz % C;

    // recover separable 1-D kernel: g[i] = sum_j w2d[i][j]  (== g[i] * sum(g) = g[i])
    if (tid < K) {
        const float* w2 = window + c * K * K + tid * K;
        float s = 0.f;
        #pragma unroll
        for (int j = 0; j < K; ++j) s += w2[j];
        gwin[tid] = s;
    }

    const int ox = blockIdx.x * TILE, oy = blockIdx.y * TILE;
    const size_t base = (size_t)bz * H * W;
    const float eps = 1e-6f, hiv = 1.0f - 1e-6f;

    // stage clipped inputs (with halo); zero padding outside the image
    for (int i = tid; i < REG * REG; i += 256) {
        int r = i / REG, cc = i % REG;
        int gy = oy - PAD + r, gx = ox - PAD + cc;
        float a = 0.f, b = 0.f;
        if (gy >= 0 && gy < H && gx >= 0 && gx < W) {
            size_t idx = base + (size_t)gy * W + gx;
            a = fminf(fmaxf(img1[idx], eps), hiv);
            b = fminf(fmaxf(img2[idx], eps), hiv);
        }
        tile[r][cc] = make_float2(a, b);
    }
    __syncthreads();

    // vertical pass: 16 output rows x 26 cols, 5 fields
    for (int i = tid; i < TILE * REG; i += 256) {
        int r = i / REG, cc = i % REG;
        float s1 = 0.f, s2 = 0.f, s11 = 0.f, s22 = 0.f, s12 = 0.f;
        #pragma unroll
        for (int ky = 0; ky < K; ++ky) {
            float gv = gwin[ky];
            float2 x = tile[r + ky][cc];
            float ga = gv * x.x;
            float gb = gv * x.y;
            s1  += ga;
            s2  += gb;
            s11 += ga * x.x;
            s22 += gb * x.y;
            s12 += ga * x.y;
        }
        v1[r][cc] = s1;  v2[r][cc] = s2;
        v11[r][cc] = s11; v22[r][cc] = s22; v12[r][cc] = s12;
    }
    __syncthreads();

    // horizontal pass: one output pixel per thread
    float m1 = 0.f, m2 = 0.f, e11 = 0.f, e22 = 0.f, e12 = 0.f;
    #pragma unroll
    for (int kx = 0; kx < K; ++kx) {
        float gv = gwin[kx];
        m1  += gv * v1[ty][tx + kx];
        m2  += gv * v2[ty][tx + kx];
        e11 += gv * v11[ty][tx + kx];
        e22 += gv * v22[ty][tx + kx];
        e12 += gv * v12[ty][tx + kx];
    }

    float mu11 = m1 * m1, mu22 = m2 * m2, mu12 = m1 * m2;
    float s1sq = e11 - mu11, s2sq = e22 - mu22, s12v = e12 - mu12;
    const float C1 = 1e-4f, C2 = 9e-4f;
    float num = (2.f * mu12 + C1) * (2.f * s12v + C2);
    float den = (mu11 + mu22 + C1) * (s1sq + s2sq + C2);
    float ssim = num / den;

    // block reduction: wave-64 shuffle, then cross-wave via LDS
    float v = ssim;
    #pragma unroll
    for (int off = 32; off > 0; off >>= 1) v += __shfl_down(v, off, 64);
    if ((tid & 63) == 0) wsum[tid >> 6] = v;
    __syncthreads();
    if (tid == 0) {
        atomicAdd(acc, wsum[0] + wsum[1] + wsum[2] + wsum[3]);
    }
}

__global__ void ssim_finalize(const float* __restrict__ acc,
                              float* __restrict__ out, float invN)
{
    out[0] = 1.0f - acc[0] * invN;
}

extern "C" void kernel_launch(void* const* d_in, const int* in_sizes, int n_in,
                              void* d_out, int out_size, void* d_ws, size_t ws_size,
                              hipStream_t stream) {
    const float* img1 = (const float*)d_in[0];
    const float* img2 = (const float*)d_in[1];
    const float* window = (const float*)d_in[2];
    float* out = (float*)d_out;
    float* acc = (float*)d_ws;

    const int B = 16, C = 3, H = 512, W = 512;
    const float invN = 1.0f / ((float)B * C * H * W);

    // d_ws is poisoned (0xAA) before every call: zero the accumulator
    hipMemsetAsync(acc, 0, sizeof(float), stream);

    dim3 block(TILE, TILE);
    dim3 grid(W / TILE, H / TILE, B * C);
    ssim_kernel<<<grid, block, 0, stream>>>(img1, img2, window, acc, H, W, C);
    ssim_finalize<<<1, 1, 0, stream>>>(acc, out, invN);
}

// Round 2
// 274.685 us; speedup vs baseline: 2.7019x; 2.7019x over previous
//
#include <hip/hip_runtime.h>

#define K 11
#define PAD 5              // K/2
#define TS 32              // output tile (32x32)
#define HT (TS + K - 1)    // 42 = tile + halo
#define LSTR 43            // padded LDS stride (odd -> conflict-free row offsets)

// Fused SSIM: clip -> 5 depthwise separable 11x11 convs -> ssim map -> sum
__global__ __launch_bounds__(256) void ssim_kernel(
    const float* __restrict__ img1, const float* __restrict__ img2,
    const float* __restrict__ window, float* __restrict__ acc,
    int H, int W, int C)
{
    __shared__ float2 tile[HT][LSTR];   // clipped (x1,x2), zero outside image
    __shared__ float4 vA[TS][LSTR];     // vertical pass: (s1, s2, s11, s22)
    __shared__ float  vB[TS][LSTR];     // vertical pass: s12
    __shared__ float  gwin[K];
    __shared__ float  wsum[4];

    const int tid = threadIdx.x;
    const int bz = blockIdx.z;
    const int c = bz % C;

    // separable 1-D kernel: g[i] = sum_j w2d[i][j] (= g[i] since sum(g)=1)
    if (tid < K) {
        const float* w2 = window + c * K * K + tid * K;
        float s = 0.f;
        #pragma unroll
        for (int j = 0; j < K; ++j) s += w2[j];
        gwin[tid] = s;
    }

    const int ox = blockIdx.x * TS, oy = blockIdx.y * TS;
    const size_t base = (size_t)bz * H * W;
    const float eps = 1e-6f, hiv = 1.0f - 1e-6f;

    // stage clipped inputs (with halo); zero padding outside the image
    for (int i = tid; i < HT * HT; i += 256) {
        int r = i / HT, cc = i % HT;
        int gy = oy - PAD + r, gx = ox - PAD + cc;
        float a = 0.f, b = 0.f;
        if (gy >= 0 && gy < H && gx >= 0 && gx < W) {
            size_t idx = base + (size_t)gy * W + gx;
            a = fminf(fmaxf(img1[idx], eps), hiv);
            b = fminf(fmaxf(img2[idx], eps), hiv);
        }
        tile[r][cc] = make_float2(a, b);
    }
    __syncthreads();

    // gaussian taps in registers
    float g[K];
    #pragma unroll
    for (int k = 0; k < K; ++k) g[k] = gwin[k];

    // vertical pass: 32 output rows x 42 cols, 5 fields, packed stores
    for (int i = tid; i < TS * HT; i += 256) {
        int r = i / HT, cc = i % HT;
        float s1 = 0.f, s2 = 0.f, s11 = 0.f, s22 = 0.f, s12 = 0.f;
        #pragma unroll
        for (int ky = 0; ky < K; ++ky) {
            float gv = g[ky];
            float2 x = tile[r + ky][cc];
            float ga = gv * x.x, gb = gv * x.y;
            s1  += ga;        s2  += gb;
            s11 += ga * x.x;  s22 += gb * x.y;  s12 += ga * x.y;
        }
        vA[r][cc] = make_float4(s1, s2, s11, s22);
        vB[r][cc] = s12;
    }
    __syncthreads();

    // horizontal pass: 4 adjacent pixels per thread, shared tap reads
    const int row = tid >> 3;          // 0..31
    const int cx  = (tid & 7) * 4;     // 0,4,...,28
    float m1[4]  = {0,0,0,0}, m2[4]  = {0,0,0,0};
    float e11[4] = {0,0,0,0}, e22[4] = {0,0,0,0}, e12[4] = {0,0,0,0};
    #pragma unroll
    for (int kx = 0; kx < K + 3; ++kx) {     // 14 reads cover 4 pixels x 11 taps
        float4 A  = vA[row][cx + kx];
        float  Bv = vB[row][cx + kx];
        #pragma unroll
        for (int p = 0; p < 4; ++p) {
            int kk = kx - p;
            if (kk >= 0 && kk < K) {
                float gv = g[kk];
                m1[p]  += gv * A.x;  m2[p]  += gv * A.y;
                e11[p] += gv * A.z;  e22[p] += gv * A.w;
                e12[p] += gv * Bv;
            }
        }
    }

    // ssim map + per-thread sum over the 4 pixels
    float vsum = 0.f;
    const float C1 = 1e-4f, C2 = 9e-4f;
    #pragma unroll
    for (int p = 0; p < 4; ++p) {
        float mu11 = m1[p] * m1[p], mu22 = m2[p] * m2[p], mu12 = m1[p] * m2[p];
        float s1sq = e11[p] - mu11, s2sq = e22[p] - mu22, s12v = e12[p] - mu12;
        float num = (2.f * mu12 + C1) * (2.f * s12v + C2);
        float den = (mu11 + mu22 + C1) * (s1sq + s2sq + C2);
        vsum += num / den;
    }

    // block reduction: wave-64 shuffle, then cross-wave via LDS, one atomic
    #pragma unroll
    for (int off = 32; off > 0; off >>= 1) vsum += __shfl_down(vsum, off, 64);
    if ((tid & 63) == 0) wsum[tid >> 6] = vsum;
    __syncthreads();
    if (tid == 0) {
        atomicAdd(acc, wsum[0] + wsum[1] + wsum[2] + wsum[3]);
    }
}

__global__ void ssim_finalize(const float* __restrict__ acc,
                              float* __restrict__ out, float invN)
{
    out[0] = 1.0f - acc[0] * invN;
}

extern "C" void kernel_launch(void* const* d_in, const int* in_sizes, int n_in,
                              void* d_out, int out_size, void* d_ws, size_t ws_size,
                              hipStream_t stream) {
    const float* img1 = (const float*)d_in[0];
    const float* img2 = (const float*)d_in[1];
    const float* window = (const float*)d_in[2];
    float* out = (float*)d_out;
    float* acc = (float*)d_ws;

    const int B = 16, C = 3, H = 512, W = 512;
    const float invN = 1.0f / ((float)B * C * H * W);

    // d_ws is poisoned (0xAA) before every call: zero the accumulator
    hipMemsetAsync(acc, 0, sizeof(float), stream);

    dim3 block(256);
    dim3 grid(W / TS, H / TS, B * C);
    ssim_kernel<<<grid, block, 0, stream>>>(img1, img2, window, acc, H, W, C);
    ssim_finalize<<<1, 1, 0, stream>>>(acc, out, invN);
}